// Round 2
// baseline (257.902 us; speedup 1.0000x reference)
//
#include <hip/hip_runtime.h>
#include <hip/hip_bf16.h>
#include <stdint.h>

#define S_LEN 4096
#define E_DIM 2048
#define DH    128

typedef __bf16 bf16_t;
typedef bf16_t bf16x8 __attribute__((ext_vector_type(8)));
typedef float  f32x4  __attribute__((ext_vector_type(4)));

__device__ __forceinline__ unsigned short f2bf(float f) {
  union { float f; uint32_t u; } v; v.f = f;
  uint32_t u = v.u;
  uint32_t r = (u + 0x7fffu + ((u >> 16) & 1u)) >> 16;  // RNE
  return (unsigned short)r;
}

__device__ __forceinline__ bf16x8 ld_bf16x8(const unsigned short* p) {
  return *(const bf16x8*)p;
}

__device__ __forceinline__ f32x4 mfma16(bf16x8 a, bf16x8 b, f32x4 c) {
  return __builtin_amdgcn_mfma_f32_16x16x32_bf16(a, b, c, 0, 0, 0);
}

// ---------------------------------------------------------------------------
// prep: trig table (cos,sin) [4096][64] + W^T bf16 [384][2048]
// ---------------------------------------------------------------------------
__global__ __launch_bounds__(256) void prep_kernel(
    const float* __restrict__ WQ, const float* __restrict__ WK,
    const float* __restrict__ WV,
    float2* __restrict__ trig, unsigned short* __restrict__ Wt)
{
  const int idx = blockIdx.x * 256 + threadIdx.x;
  if (idx < S_LEN * 64) {
    const int pos = idx >> 6, p = idx & 63;
    const float freq = powf(10000.0f, -(float)p / 64.0f);
    float sv, cv;
    sincosf((float)pos * freq, &sv, &cv);
    trig[idx] = make_float2(cv, sv);
  } else {
    const int j = idx - S_LEN * 64;          // 0 .. 3*128*2048-1
    const int n = j >> 11, k = j & 2047;     // n: output col (0..383), k
    const int z = n >> 7, nl = n & 127;
    const float* W = (z == 0) ? WQ : ((z == 1) ? WK : WV);
    Wt[j] = f2bf(W[k * 128 + nl]);
  }
}

// ---------------------------------------------------------------------------
// proj: [16384 x 2048] @ [2048 x 384] -> Qb (rope, prescale), Kb, Vt (rope, T)
// 256 blocks (BM=64), 512 threads (8 waves, 2Mx4N of 32x96 each)
// ---------------------------------------------------------------------------
__global__ __launch_bounds__(512, 1) void proj_kernel(
    const float* __restrict__ x, const unsigned short* __restrict__ Wt,
    const float2* __restrict__ trig,
    unsigned short* __restrict__ Qb, unsigned short* __restrict__ Kb,
    unsigned short* __restrict__ Vt)
{
  __shared__ __align__(16) unsigned short xlds[64][40];  // BK=32, pad->2-way
  const int tid  = threadIdx.x;
  const int m0   = blockIdx.x * 64;
  const int lane = tid & 63, w = tid >> 6;
  const int wr = w >> 2, wc = w & 3;
  const int col = lane & 15, kg = lane >> 4;

  f32x4 acc[2][6];
  #pragma unroll
  for (int i = 0; i < 2; i++)
    #pragma unroll
    for (int j = 0; j < 6; j++) acc[i][j] = (f32x4){0.f, 0.f, 0.f, 0.f};

  const int sr = tid >> 3;          // stage row 0..63
  const int sc = (tid & 7) * 4;     // stage col 0..28

  for (int k0 = 0; k0 < E_DIM; k0 += 32) {
    float4 xv = *(const float4*)(x + (size_t)(m0 + sr) * E_DIM + k0 + sc);
    __syncthreads();                // protect previous iter's reads
    ushort4 h;
    h.x = f2bf(xv.x); h.y = f2bf(xv.y); h.z = f2bf(xv.z); h.w = f2bf(xv.w);
    *(ushort4*)(&xlds[sr][sc]) = h;
    __syncthreads();

    bf16x8 a0 = ld_bf16x8(&xlds[wr * 32 + col][kg * 8]);
    bf16x8 a1 = ld_bf16x8(&xlds[wr * 32 + 16 + col][kg * 8]);
    #pragma unroll
    for (int nt = 0; nt < 6; nt++) {
      const int n = wc * 96 + nt * 16 + col;
      bf16x8 b = ld_bf16x8(Wt + (size_t)n * E_DIM + k0 + kg * 8);
      acc[0][nt] = mfma16(a0, b, acc[0][nt]);
      acc[1][nt] = mfma16(a1, b, acc[1][nt]);
    }
  }

  // epilogue: D layout col = lane&15 (n), row = (lane>>4)*4 + r (m)
  #pragma unroll
  for (int mt = 0; mt < 2; mt++) {
    const int mbase = m0 + wr * 32 + mt * 16 + kg * 4;  // + r
    const int spos  = mbase & 4095;
    const int bb    = mbase >> 12;
    #pragma unroll
    for (int nt = 0; nt < 6; nt++) {
      const int n = wc * 96 + nt * 16 + col;
      const int z = n >> 7, d = n & 127;   // z uniform across the wave
      f32x4 v = acc[mt][nt];
      if (z == 1) {                        // K: no rope
        #pragma unroll
        for (int r = 0; r < 4; r++)
          Kb[(size_t)(mbase + r) * DH + d] = f2bf(v[r]);
      } else {                             // Q or V: rope
        const float sgn  = (d & 1) ? 1.0f : -1.0f;
        const int   pidx = d >> 1;
        float ov[4];
        #pragma unroll
        for (int r = 0; r < 4; r++) {
          float  pv = __shfl_xor(v[r], 1, 64);
          float2 cs = trig[(spos + r) * 64 + pidx];
          ov[r] = v[r] * cs.x + sgn * pv * cs.y;
        }
        if (z == 0) {                      // Q: prescale by 1/sqrt(128)
          #pragma unroll
          for (int r = 0; r < 4; r++)
            Qb[(size_t)(mbase + r) * DH + d] =
                f2bf(ov[r] * 0.08838834764831845f);
        } else {                           // V: write transposed [b][d][s]
          ushort4 pk;
          pk.x = f2bf(ov[0]); pk.y = f2bf(ov[1]);
          pk.z = f2bf(ov[2]); pk.w = f2bf(ov[3]);
          *(ushort4*)(Vt + ((size_t)(bb * DH + d)) * S_LEN + spos) = pk;
        }
      }
    }
  }
}

// ---------------------------------------------------------------------------
// flash: causal attention. grid (64, 4), 256 threads (4 waves x 16 q-rows)
// ---------------------------------------------------------------------------
__global__ __launch_bounds__(256, 1) void flash_kernel(
    const unsigned short* __restrict__ Qb, const unsigned short* __restrict__ Kb,
    const unsigned short* __restrict__ Vt, float* __restrict__ out)
{
  __shared__ __align__(16) unsigned short Ktile[64 * 128];   // swizzled
  __shared__ __align__(16) unsigned short Vtile[128 * 64];   // swizzled, d-major
  __shared__ __align__(16) unsigned short Plds[4][16][72];   // per-wave, padded

  const int b   = blockIdx.y;
  const int q0  = blockIdx.x * 64;
  const int tid = threadIdx.x;
  const int lane = tid & 63, w = tid >> 6;
  const int col = lane & 15, kg = lane >> 4;

  // Q fragments: A layout row = lane&15, k = (lane>>4)*8+e (+32 per chunk)
  bf16x8 qf[4];
  {
    const unsigned short* qrow =
        Qb + (size_t)(b * S_LEN + q0 + w * 16 + col) * DH;
    #pragma unroll
    for (int kk = 0; kk < 4; kk++)
      qf[kk] = ld_bf16x8(qrow + kk * 32 + kg * 8);
  }

  f32x4 o[8];
  #pragma unroll
  for (int i = 0; i < 8; i++) o[i] = (f32x4){0.f, 0.f, 0.f, 0.f};
  float mrow[4] = {-1e30f, -1e30f, -1e30f, -1e30f};
  float lrow[4] = {0.f, 0.f, 0.f, 0.f};

  const unsigned short* Kbase = Kb + (size_t)b * S_LEN * DH;
  const unsigned short* Vbase = Vt + (size_t)b * DH * S_LEN;

  for (int kv0 = 0; kv0 <= q0; kv0 += 64) {
    // ---- stage K [64][128] and Vt [128][64], XOR swizzle (row&7)<<4
    {
      const int kr  = tid >> 4;          // 0..15
      const int kcb = (tid & 15) * 16;   // byte col (256B rows)
      #pragma unroll
      for (int rr = 0; rr < 4; rr++) {
        const int r = rr * 16 + kr;
        uint4 vv = *(const uint4*)(Kbase + (size_t)(kv0 + r) * DH + (tid & 15) * 8);
        *(uint4*)((char*)Ktile + r * 256 + (kcb ^ ((r & 7) << 4))) = vv;
      }
      const int vr  = tid >> 3;          // 0..31
      const int vcb = (tid & 7) * 16;    // byte col (128B rows)
      #pragma unroll
      for (int rr = 0; rr < 4; rr++) {
        const int dD = rr * 32 + vr;
        uint4 vv = *(const uint4*)(Vbase + (size_t)dD * S_LEN + kv0 + (tid & 7) * 8);
        *(uint4*)((char*)Vtile + dD * 128 + (vcb ^ ((dD & 7) << 4))) = vv;
      }
    }
    __syncthreads();

    // ---- S = Q K^T  (D: col = key, row = q)
    f32x4 st[4];
    #pragma unroll
    for (int kb = 0; kb < 4; kb++) {
      f32x4 sacc = (f32x4){0.f, 0.f, 0.f, 0.f};
      const int krow = kb * 16 + col;
      #pragma unroll
      for (int kk = 0; kk < 4; kk++) {
        bf16x8 kf = *(const bf16x8*)((const char*)Ktile + krow * 256 +
                                     ((kk * 64 + kg * 16) ^ ((krow & 7) << 4)));
        sacc = mfma16(qf[kk], kf, sacc);
      }
      st[kb] = sacc;
    }

    // ---- causal mask (single diagonal tile since QBLK==KVBLK)
    if (kv0 == q0) {
      #pragma unroll
      for (int kb = 0; kb < 4; kb++) {
        const int key = kv0 + kb * 16 + col;
        #pragma unroll
        for (int r = 0; r < 4; r++) {
          const int q = q0 + w * 16 + kg * 4 + r;
          if (key > q) st[kb][r] = -1e30f;
        }
      }
    }

    // ---- online softmax (per-lane partial m/l; 16-lane group reduce)
    float scale[4];
    #pragma unroll
    for (int r = 0; r < 4; r++) {
      float mx = fmaxf(fmaxf(st[0][r], st[1][r]), fmaxf(st[2][r], st[3][r]));
      #pragma unroll
      for (int off = 1; off < 16; off <<= 1)
        mx = fmaxf(mx, __shfl_xor(mx, off, 64));
      const float mnew = fmaxf(mrow[r], mx);
      scale[r] = __expf(mrow[r] - mnew);
      mrow[r] = mnew;
      float psum = 0.f;
      #pragma unroll
      for (int kb = 0; kb < 4; kb++) {
        float p = __expf(st[kb][r] - mnew);
        st[kb][r] = p;
        psum += p;
      }
      lrow[r] = lrow[r] * scale[r] + psum;
    }
    #pragma unroll
    for (int nt = 0; nt < 8; nt++)
      #pragma unroll
      for (int r = 0; r < 4; r++)
        o[nt][r] *= scale[r];

    // ---- P -> per-wave LDS (re-layout to A fragment)
    #pragma unroll
    for (int kb = 0; kb < 4; kb++)
      #pragma unroll
      for (int r = 0; r < 4; r++)
        Plds[w][kg * 4 + r][kb * 16 + col] = f2bf(st[kb][r]);

    // ---- O += P V   (A = P row=q; B = V col=d, k=key via Vt rows)
    #pragma unroll
    for (int kc = 0; kc < 2; kc++) {
      bf16x8 pa = ld_bf16x8(&Plds[w][col][kc * 32 + kg * 8]);
      #pragma unroll
      for (int nt = 0; nt < 8; nt++) {
        const int vrow = nt * 16 + col;
        bf16x8 vf = *(const bf16x8*)((const char*)Vtile + vrow * 128 +
                                     ((kc * 64 + kg * 16) ^ ((vrow & 7) << 4)));
        o[nt] = mfma16(pa, vf, o[nt]);
      }
    }
    __syncthreads();
  }

  // ---- finalize: reduce l across 16-lane group, divide, store f32
  float inv[4];
  #pragma unroll
  for (int r = 0; r < 4; r++) {
    float l = lrow[r];
    #pragma unroll
    for (int off = 1; off < 16; off <<= 1)
      l += __shfl_xor(l, off, 64);
    inv[r] = 1.0f / l;
  }
  float* orow = out + (size_t)(b * S_LEN + q0 + w * 16 + kg * 4) * DH;
  #pragma unroll
  for (int nt = 0; nt < 8; nt++)
    #pragma unroll
    for (int r = 0; r < 4; r++)
      orow[r * DH + nt * 16 + col] = o[nt][r] * inv[r];
}

// ---------------------------------------------------------------------------
extern "C" void kernel_launch(void* const* d_in, const int* in_sizes, int n_in,
                              void* d_out, int out_size, void* d_ws, size_t ws_size,
                              hipStream_t stream) {
  const float* x  = (const float*)d_in[0];
  const float* WQ = (const float*)d_in[1];
  const float* WK = (const float*)d_in[2];
  const float* WV = (const float*)d_in[3];
  float* out = (float*)d_out;

  char* ws = (char*)d_ws;
  float2*         trig = (float2*)(ws);                      // 2 MB
  unsigned short* Wt   = (unsigned short*)(ws + (2u << 20)); // 1.5 MB
  unsigned short* Qb   = (unsigned short*)(ws + (4u << 20)); // 4 MB
  unsigned short* Kb   = (unsigned short*)(ws + (8u << 20)); // 4 MB
  unsigned short* Vt   = (unsigned short*)(ws + (12u << 20));// 4 MB (ends 16MB)

  hipLaunchKernelGGL(prep_kernel, dim3(4096), dim3(256), 0, stream,
                     WQ, WK, WV, trig, Wt);
  hipLaunchKernelGGL(proj_kernel, dim3(256), dim3(512), 0, stream,
                     x, Wt, trig, Qb, Kb, Vt);
  hipLaunchKernelGGL(flash_kernel, dim3(64, 4), dim3(256), 0, stream,
                     Qb, Kb, Vt, out);
}